// Round 1
// baseline (64.382 us; speedup 1.0000x reference)
//
#include <hip/hip_runtime.h>

// LocalDecoder: per-edge gather + 2 stacked MLPs (256->64->64->1), bf16 MFMA.
//
// ws layout (bytes), produced by prep_kernel:
//   OFF_W1: bf16 W1frag[2][5][4][64][8]  (f, kk, nn, lane, j)  = 40960
//   OFF_W2: bf16 W2frag[2][2][4][64][8]                        = 16384
//   OFF_B1: f32 bias1p[2][64]  (b1 + h_global/enc_global folded)
//   OFF_B2: f32 b2[2][64]
//   OFF_W3: f32 w3[2][64]
//   OFF_B3: f32 b3[2] (padded to 64B)

#define OFF_W1 0
#define OFF_W2 40960
#define OFF_B1 57344
#define OFF_B2 57856
#define OFF_W3 58368
#define OFF_B3 58880
#define W_TOTAL 58944
#define H1_OFF 58944            // per-wave h1 scratch [16][72] bf16 = 2304 B
#define LDS_TOTAL (H1_OFF + 4 * 2304)

typedef __attribute__((ext_vector_type(8))) short bf16x8;
typedef __attribute__((ext_vector_type(4))) float f32x4;

__device__ inline short f2bf(float f) {
    unsigned u = __builtin_bit_cast(unsigned, f);
    u += 0x7FFFu + ((u >> 16) & 1u);      // round-to-nearest-even
    return (short)(u >> 16);
}

__device__ inline float4 ld4(const float* p, bool v) {
    if (v) return *(const float4*)p;
    return make_float4(0.f, 0.f, 0.f, 0.f);
}

__device__ inline bf16x8 pack8(float4 a, float4 b) {
    bf16x8 r;
    r[0] = f2bf(a.x); r[1] = f2bf(a.y); r[2] = f2bf(a.z); r[3] = f2bf(a.w);
    r[4] = f2bf(b.x); r[5] = f2bf(b.y); r[6] = f2bf(b.z); r[7] = f2bf(b.w);
    return r;
}

// ---------------- prep: fold globals into bias, swizzle W into fragment order
__global__ void prep_kernel(const float* __restrict__ W1, const float* __restrict__ b1,
                            const float* __restrict__ W2, const float* __restrict__ b2,
                            const float* __restrict__ W3, const float* __restrict__ b3,
                            const float* __restrict__ h_global, const float* __restrict__ enc_global,
                            char* __restrict__ ws) {
    int idx = blockIdx.x * 256 + threadIdx.x;
    short* w1f = (short*)(ws + OFF_W1);
    short* w2f = (short*)(ws + OFF_W2);
    float* bp1 = (float*)(ws + OFF_B1);
    float* bp2 = (float*)(ws + OFF_B2);
    float* wp3 = (float*)(ws + OFF_W3);
    float* bp3 = (float*)(ws + OFF_B3);
    if (idx < 20480) {                       // W1 fragments, K-tile dims: [gf 0:64 | gt 64:128 | encl 128:160]
        int f = idx / 10240, r0 = idx % 10240;
        int kk = r0 / 2048, r1 = r0 % 2048;
        int nn = r1 / 512,  r2 = r1 % 512;
        int l = r2 / 8,     j = r2 % 8;
        int kt = kk * 32 + (l >> 4) * 8 + j;             // 0..159
        int r = (kt < 128) ? kt : kt + 64;               // enc_local lives at rows 192..223
        int c = nn * 16 + (l & 15);
        w1f[idx] = f2bf(W1[(f * 256 + r) * 64 + c]);
    } else if (idx < 28672) {                // W2 fragments
        int i2 = idx - 20480;
        int f = i2 / 4096, r0 = i2 % 4096;
        int kk = r0 / 2048, r1 = r0 % 2048;
        int nn = r1 / 512,  r2 = r1 % 512;
        int l = r2 / 8,     j = r2 % 8;
        int k = kk * 32 + (l >> 4) * 8 + j;
        int c = nn * 16 + (l & 15);
        w2f[i2] = f2bf(W2[(f * 64 + k) * 64 + c]);
    } else if (idx < 28800) {                // bias1' = b1 + globals @ W1 (full fp32)
        int i3 = idx - 28672; int f = i3 / 64, o = i3 % 64;
        float s = b1[f * 64 + o];
        for (int t = 0; t < 64; ++t) s += h_global[t] * W1[(f * 256 + 128 + t) * 64 + o];
        for (int t = 0; t < 32; ++t) s += enc_global[t] * W1[(f * 256 + 224 + t) * 64 + o];
        bp1[i3] = s;
    } else if (idx < 28928) {
        int i4 = idx - 28800; bp2[i4] = b2[i4];
    } else if (idx < 29056) {
        int i5 = idx - 28928; wp3[i5] = W3[i5];          // W3 is [2][64][1]
    } else if (idx < 29058) {
        bp3[idx - 29056] = b3[idx - 29056];
    }
}

// ---------------- main kernel: 4 waves x 4 tiles x 16 edges = 256 edges/block
__global__ __launch_bounds__(256, 2) void main_kernel(
        const float* __restrict__ edge_array, const float* __restrict__ h_local,
        const float* __restrict__ enc_local,
        const int* __restrict__ addr_from, const int* __restrict__ addr_to,
        const char* __restrict__ ws, float* __restrict__ out,
        int n_edges, int n_nodes) {
    __shared__ __align__(16) char lds[LDS_TOTAL];
    const int tid = threadIdx.x;
    const int lane = tid & 63, wave = tid >> 6;

    // stage prepped W block into LDS (linear float4 copy, 57344 + 1600 B)
    #pragma unroll
    for (int it = 0; it < 14; ++it)
        ((float4*)lds)[it * 256 + tid] = ((const float4*)ws)[it * 256 + tid];
    if (tid < 100)
        ((float4*)(lds + 57344))[tid] = ((const float4*)(ws + 57344))[tid];
    __syncthreads();

    const float* bp1 = (const float*)(lds + OFF_B1);
    const float* bp2 = (const float*)(lds + OFF_B2);
    const float* wp3 = (const float*)(lds + OFF_W3);
    const float* bp3 = (const float*)(lds + OFF_B3);
    short* h1w = (short*)(lds + H1_OFF + wave * 2304);   // [16][72] bf16

    const int col16 = lane & 15, g = lane >> 4;

    for (int t = 0; t < 4; ++t) {
        int tbase = blockIdx.x * 256 + wave * 64 + t * 16;
        if (tbase >= n_edges) break;                     // wave-uniform
        int e = tbase + col16;
        bool ev = e < n_edges;
        int af = ev ? addr_from[e] : -1;
        int at = ev ? addr_to[e] : -1;
        bool afv = (unsigned)af < (unsigned)n_nodes;
        bool atv = (unsigned)at < (unsigned)n_nodes;
        const float* pf = h_local + (size_t)(afv ? af : 0) * 64 + g * 8;
        const float* pt = h_local + (size_t)(atv ? at : 0) * 64 + g * 8;
        const float* pe = enc_local + (size_t)(ev ? e : 0) * 32 + g * 8;

        bf16x8 a1[5];                                    // A frags: row = lane&15 (edge), k = g*8+j
        a1[0] = pack8(ld4(pf,      afv), ld4(pf + 4,  afv));
        a1[1] = pack8(ld4(pf + 32, afv), ld4(pf + 36, afv));
        a1[2] = pack8(ld4(pt,      atv), ld4(pt + 4,  atv));
        a1[3] = pack8(ld4(pt + 32, atv), ld4(pt + 36, atv));
        a1[4] = pack8(ld4(pe,      ev ), ld4(pe + 4,  ev ));

        #pragma unroll
        for (int f = 0; f < 2; ++f) {
            f32x4 zero = {0.f, 0.f, 0.f, 0.f};
            f32x4 acc1[4] = {zero, zero, zero, zero};
            #pragma unroll
            for (int kk = 0; kk < 5; ++kk)
                #pragma unroll
                for (int nn = 0; nn < 4; ++nn) {
                    bf16x8 b = *(const bf16x8*)(lds + OFF_W1 + ((f * 5 + kk) * 4 + nn) * 1024 + lane * 16);
                    acc1[nn] = __builtin_amdgcn_mfma_f32_16x16x32_bf16(a1[kk], b, acc1[nn], 0, 0, 0);
                }

            // bias + leaky_relu, write h1 to LDS (D layout: row=g*4+j (edge), col=col16+16nn)
            #pragma unroll
            for (int nn = 0; nn < 4; ++nn) {
                float bv = bp1[f * 64 + col16 + 16 * nn];
                #pragma unroll
                for (int j = 0; j < 4; ++j) {
                    float v = acc1[nn][j] + bv;
                    v = v > 0.f ? v : 0.01f * v;
                    h1w[(g * 4 + j) * 72 + col16 + 16 * nn] = f2bf(v);
                }
            }
            asm volatile("s_waitcnt lgkmcnt(0)" ::: "memory");   // wave-internal LDS transpose

            bf16x8 a2[2];                                // A frags for layer 2: row=col16 (edge), k=g*8+j
            a2[0] = *(const bf16x8*)((const char*)h1w + col16 * 144 + g * 16);
            a2[1] = *(const bf16x8*)((const char*)h1w + col16 * 144 + 64 + g * 16);

            f32x4 acc2[4] = {zero, zero, zero, zero};
            #pragma unroll
            for (int kk = 0; kk < 2; ++kk)
                #pragma unroll
                for (int nn = 0; nn < 4; ++nn) {
                    bf16x8 b = *(const bf16x8*)(lds + OFF_W2 + ((f * 2 + kk) * 4 + nn) * 1024 + lane * 16);
                    acc2[nn] = __builtin_amdgcn_mfma_f32_16x16x32_bf16(a2[kk], b, acc2[nn], 0, 0, 0);
                }

            // layer 3: per-lane partial dot, reduce across the 16 cols
            float p[4] = {0.f, 0.f, 0.f, 0.f};
            #pragma unroll
            for (int nn = 0; nn < 4; ++nn) {
                float b2v = bp2[f * 64 + col16 + 16 * nn];
                float w3v = wp3[f * 64 + col16 + 16 * nn];
                #pragma unroll
                for (int j = 0; j < 4; ++j) {
                    float h = acc2[nn][j] + b2v;
                    h = h > 0.f ? h : 0.01f * h;
                    p[j] += h * w3v;
                }
            }
            #pragma unroll
            for (int m = 1; m <= 8; m <<= 1) {
                #pragma unroll
                for (int j = 0; j < 4; ++j) p[j] += __shfl_xor(p[j], m, 64);
            }
            if (col16 == 0) {
                float b3v = bp3[f];
                #pragma unroll
                for (int j = 0; j < 4; ++j) {
                    int ee = tbase + g * 4 + j;
                    if (ee < n_edges) {
                        float val = p[j] + b3v;
                        float ea = edge_array[4 * ee];
                        if (__builtin_isnan(ea)) val = __builtin_nanf("");
                        out[f * n_edges + ee] = val;
                    }
                }
            }
        }
    }
}

extern "C" void kernel_launch(void* const* d_in, const int* in_sizes, int n_in,
                              void* d_out, int out_size, void* d_ws, size_t ws_size,
                              hipStream_t stream) {
    const float* edge_array = (const float*)d_in[0];
    const float* h_local    = (const float*)d_in[1];
    const float* h_global   = (const float*)d_in[2];
    const float* enc_local  = (const float*)d_in[3];
    const float* enc_global = (const float*)d_in[4];
    const float* W1 = (const float*)d_in[5];
    const float* b1 = (const float*)d_in[6];
    const float* W2 = (const float*)d_in[7];
    const float* b2 = (const float*)d_in[8];
    const float* W3 = (const float*)d_in[9];
    const float* b3 = (const float*)d_in[10];
    const int* addr_from = (const int*)d_in[11];
    const int* addr_to   = (const int*)d_in[12];
    int n_edges = in_sizes[11];
    int n_nodes = in_sizes[1] / 64;
    char* ws = (char*)d_ws;

    hipLaunchKernelGGL(prep_kernel, dim3(114), dim3(256), 0, stream,
                       W1, b1, W2, b2, W3, b3, h_global, enc_global, ws);
    int nblk = (n_edges + 255) / 256;
    hipLaunchKernelGGL(main_kernel, dim3(nblk), dim3(256), 0, stream,
                       edge_array, h_local, enc_local, addr_from, addr_to,
                       ws, (float*)d_out, n_edges, n_nodes);
}

// Round 2
// 51.500 us; speedup vs baseline: 1.2501x; 1.2501x over previous
//
#include <hip/hip_runtime.h>

// LocalDecoder: per-edge gather + 2 stacked MLPs (256->64->64->1), bf16 MFMA.
//
// ws layout (bytes):
//   OFF_W1: bf16 W1frag[2][5][4][64][8]  (f, kk, nn, lane, j)  = 40960
//   OFF_W2: bf16 W2frag[2][2][4][64][8]                        = 16384
//   OFF_B1: f32 bias1p[2][64]  (b1 + h_global/enc_global folded)
//   OFF_B2: f32 b2[2][64];  OFF_W3: f32 w3[2][64];  OFF_B3: f32 b3[2]
//   OFF_HBF: bf16 h_local[n_nodes][64] (prep-converted; only if ws big enough)

#define OFF_W1 0
#define OFF_W2 40960
#define OFF_B1 57344
#define OFF_B2 57856
#define OFF_W3 58368
#define OFF_B3 58880
#define W_TOTAL 58944
#define OFF_HBF 59392
#define H1_OFF 58944            // per-wave h1 scratch [16][72] bf16 = 2304 B
#define NWAVE 8
#define LDS_TOTAL (H1_OFF + NWAVE * 2304)

typedef __attribute__((ext_vector_type(8))) short bf16x8;
typedef __attribute__((ext_vector_type(4))) float f32x4;

__device__ inline short f2bf(float f) {
    unsigned u = __builtin_bit_cast(unsigned, f);
    u += 0x7FFFu + ((u >> 16) & 1u);      // round-to-nearest-even
    return (short)(u >> 16);
}

__device__ inline float4 ld4(const float* p, bool v) {
    if (v) return *(const float4*)p;
    return make_float4(0.f, 0.f, 0.f, 0.f);
}

__device__ inline bf16x8 pack8(float4 a, float4 b) {
    bf16x8 r;
    r[0] = f2bf(a.x); r[1] = f2bf(a.y); r[2] = f2bf(a.z); r[3] = f2bf(a.w);
    r[4] = f2bf(b.x); r[5] = f2bf(b.y); r[6] = f2bf(b.z); r[7] = f2bf(b.w);
    return r;
}

// ---------------- prep: fold globals into bias, swizzle W into fragment order
__global__ void prep_kernel(const float* __restrict__ W1, const float* __restrict__ b1,
                            const float* __restrict__ W2, const float* __restrict__ b2,
                            const float* __restrict__ W3, const float* __restrict__ b3,
                            const float* __restrict__ h_global, const float* __restrict__ enc_global,
                            char* __restrict__ ws) {
    int idx = blockIdx.x * 256 + threadIdx.x;
    short* w1f = (short*)(ws + OFF_W1);
    short* w2f = (short*)(ws + OFF_W2);
    float* bp1 = (float*)(ws + OFF_B1);
    float* bp2 = (float*)(ws + OFF_B2);
    float* wp3 = (float*)(ws + OFF_W3);
    float* bp3 = (float*)(ws + OFF_B3);
    if (idx < 20480) {                       // W1 fragments, K dims: [gf 0:64 | gt 64:128 | encl 128:160]
        int f = idx / 10240, r0 = idx % 10240;
        int kk = r0 / 2048, r1 = r0 % 2048;
        int nn = r1 / 512,  r2 = r1 % 512;
        int l = r2 / 8,     j = r2 % 8;
        int kt = kk * 32 + (l >> 4) * 8 + j;             // 0..159
        int r = (kt < 128) ? kt : kt + 64;               // enc_local rows live at 192..223
        int c = nn * 16 + (l & 15);
        w1f[idx] = f2bf(W1[(f * 256 + r) * 64 + c]);
    } else if (idx < 28672) {                // W2 fragments
        int i2 = idx - 20480;
        int f = i2 / 4096, r0 = i2 % 4096;
        int kk = r0 / 2048, r1 = r0 % 2048;
        int nn = r1 / 512,  r2 = r1 % 512;
        int l = r2 / 8,     j = r2 % 8;
        int k = kk * 32 + (l >> 4) * 8 + j;
        int c = nn * 16 + (l & 15);
        w2f[i2] = f2bf(W2[(f * 64 + k) * 64 + c]);
    } else if (idx < 28800) {                // bias1' = b1 + globals @ W1 (full fp32)
        int i3 = idx - 28672; int f = i3 / 64, o = i3 % 64;
        float s = b1[f * 64 + o];
        for (int t = 0; t < 64; ++t) s += h_global[t] * W1[(f * 256 + 128 + t) * 64 + o];
        for (int t = 0; t < 32; ++t) s += enc_global[t] * W1[(f * 256 + 224 + t) * 64 + o];
        bp1[i3] = s;
    } else if (idx < 28928) {
        int i4 = idx - 28800; bp2[i4] = b2[i4];
    } else if (idx < 29056) {
        int i5 = idx - 28928; wp3[i5] = W3[i5];          // W3 is [2][64][1]
    } else if (idx < 29058) {
        bp3[idx - 29056] = b3[idx - 29056];
    }
}

// ---------------- prep: h_local f32 -> bf16 (gather rows shrink 256B -> 128B)
__global__ void prep_hbf(const float* __restrict__ h, short* __restrict__ hb, int n8) {
    int i = blockIdx.x * 256 + threadIdx.x;
    if (i >= n8) return;
    float4 a = ((const float4*)h)[2 * i];
    float4 b = ((const float4*)h)[2 * i + 1];
    ((bf16x8*)hb)[i] = pack8(a, b);
}

// ---------------- guarded tile gather (per-lane fill-0 semantics)
template<bool HBF>
__device__ inline void load_tile(int tbase, int n_edges, int n_nodes,
        const int* __restrict__ addr_from, const int* __restrict__ addr_to,
        const float* __restrict__ h_local, const short* __restrict__ hbf,
        const float* __restrict__ enc_local, int col16, int g,
        bf16x8& f0, bf16x8& f1, bf16x8& t0, bf16x8& t1, float4& e0, float4& e1) {
    int e = tbase + col16;
    bool ev = e < n_edges;
    int af = ev ? addr_from[e] : -1;
    int at = ev ? addr_to[e] : -1;
    bool afv = (unsigned)af < (unsigned)n_nodes;
    bool atv = (unsigned)at < (unsigned)n_nodes;
    if (HBF) {
        bf16x8 z = {0, 0, 0, 0, 0, 0, 0, 0};
        const short* pf = hbf + (size_t)(afv ? af : 0) * 64 + g * 8;
        const short* pt = hbf + (size_t)(atv ? at : 0) * 64 + g * 8;
        bf16x8 v0 = *(const bf16x8*)pf, v1 = *(const bf16x8*)(pf + 32);
        bf16x8 w0 = *(const bf16x8*)pt, w1 = *(const bf16x8*)(pt + 32);
        f0 = afv ? v0 : z; f1 = afv ? v1 : z;
        t0 = atv ? w0 : z; t1 = atv ? w1 : z;
    } else {
        const float* pf = h_local + (size_t)(afv ? af : 0) * 64 + g * 8;
        const float* pt = h_local + (size_t)(atv ? at : 0) * 64 + g * 8;
        f0 = pack8(ld4(pf, afv), ld4(pf + 4, afv));
        f1 = pack8(ld4(pf + 32, afv), ld4(pf + 36, afv));
        t0 = pack8(ld4(pt, atv), ld4(pt + 4, atv));
        t1 = pack8(ld4(pt + 32, atv), ld4(pt + 36, atv));
    }
    const float* pe = enc_local + (size_t)(ev ? e : 0) * 32 + g * 8;
    e0 = ld4(pe, ev); e1 = ld4(pe + 4, ev);
}

// ---------------- main: 8 waves x 4 tiles x 16 edges = 512 edges/block
template<bool HBF>
__global__ __launch_bounds__(512, 4) void main_kernel(
        const float* __restrict__ edge_array, const float* __restrict__ h_local,
        const float* __restrict__ enc_local,
        const int* __restrict__ addr_from, const int* __restrict__ addr_to,
        const char* __restrict__ ws, float* __restrict__ out,
        int n_edges, int n_nodes) {
    __shared__ __align__(16) char lds[LDS_TOTAL];
    const int tid = threadIdx.x;
    const int lane = tid & 63, wave = tid >> 6;
    const int col16 = lane & 15, g = lane >> 4;
    const short* hbf = (const short*)(ws + OFF_HBF);
    const int base = blockIdx.x * 512 + wave * 64;

    // issue tile-0 gathers BEFORE the staging barrier (latency overlaps staging)
    bf16x8 nf0, nf1, nt0, nt1; float4 ne0, ne1;
    load_tile<HBF>(base, n_edges, n_nodes, addr_from, addr_to, h_local, hbf,
                   enc_local, col16, g, nf0, nf1, nt0, nt1, ne0, ne1);

    // stage prepped W block into LDS (linear float4 copy)
    #pragma unroll
    for (int it = 0; it < 7; ++it)
        ((float4*)lds)[it * 512 + tid] = ((const float4*)ws)[it * 512 + tid];
    if (tid < 100)
        ((float4*)(lds + 57344))[tid] = ((const float4*)(ws + 57344))[tid];
    __syncthreads();

    const float* bp1 = (const float*)(lds + OFF_B1);
    const float* bp2 = (const float*)(lds + OFF_B2);
    const float* wp3 = (const float*)(lds + OFF_W3);
    const float* bp3 = (const float*)(lds + OFF_B3);
    short* h1w = (short*)(lds + H1_OFF + wave * 2304);   // [16][72] bf16

    #pragma unroll
    for (int t = 0; t < 4; ++t) {
        int tbase = base + t * 16;
        if (tbase >= n_edges) break;                     // wave-uniform

        bf16x8 a1[5];
        a1[0] = nf0; a1[1] = nf1; a1[2] = nt0; a1[3] = nt1;
        a1[4] = pack8(ne0, ne1);
        if (t < 3)                                       // prefetch next tile during compute
            load_tile<HBF>(tbase + 16, n_edges, n_nodes, addr_from, addr_to, h_local,
                           hbf, enc_local, col16, g, nf0, nf1, nt0, nt1, ne0, ne1);

        #pragma unroll
        for (int f = 0; f < 2; ++f) {
            f32x4 zero = {0.f, 0.f, 0.f, 0.f};
            f32x4 acc1[4] = {zero, zero, zero, zero};
            #pragma unroll
            for (int kk = 0; kk < 5; ++kk)
                #pragma unroll
                for (int nn = 0; nn < 4; ++nn) {
                    bf16x8 b = *(const bf16x8*)(lds + OFF_W1 + ((f * 5 + kk) * 4 + nn) * 1024 + lane * 16);
                    acc1[nn] = __builtin_amdgcn_mfma_f32_16x16x32_bf16(a1[kk], b, acc1[nn], 0, 0, 0);
                }

            // bias + leaky_relu, write h1 to LDS (D layout: row=g*4+j (edge), col=col16+16nn)
            #pragma unroll
            for (int nn = 0; nn < 4; ++nn) {
                float bv = bp1[f * 64 + col16 + 16 * nn];
                #pragma unroll
                for (int j = 0; j < 4; ++j) {
                    float v = acc1[nn][j] + bv;
                    v = v > 0.f ? v : 0.01f * v;
                    h1w[(g * 4 + j) * 72 + col16 + 16 * nn] = f2bf(v);
                }
            }
            asm volatile("s_waitcnt lgkmcnt(0)" ::: "memory");   // wave-internal LDS transpose

            bf16x8 a2[2];                                // layer-2 A frags: row=col16 (edge), k=g*8+j
            a2[0] = *(const bf16x8*)((const char*)h1w + col16 * 144 + g * 16);
            a2[1] = *(const bf16x8*)((const char*)h1w + col16 * 144 + 64 + g * 16);

            f32x4 acc2[4] = {zero, zero, zero, zero};
            #pragma unroll
            for (int kk = 0; kk < 2; ++kk)
                #pragma unroll
                for (int nn = 0; nn < 4; ++nn) {
                    bf16x8 b = *(const bf16x8*)(lds + OFF_W2 + ((f * 2 + kk) * 4 + nn) * 1024 + lane * 16);
                    acc2[nn] = __builtin_amdgcn_mfma_f32_16x16x32_bf16(a2[kk], b, acc2[nn], 0, 0, 0);
                }

            // layer 3: per-lane partial dot, reduce across the 16 cols
            float p[4] = {0.f, 0.f, 0.f, 0.f};
            #pragma unroll
            for (int nn = 0; nn < 4; ++nn) {
                float b2v = bp2[f * 64 + col16 + 16 * nn];
                float w3v = wp3[f * 64 + col16 + 16 * nn];
                #pragma unroll
                for (int j = 0; j < 4; ++j) {
                    float h = acc2[nn][j] + b2v;
                    h = h > 0.f ? h : 0.01f * h;
                    p[j] += h * w3v;
                }
            }
            #pragma unroll
            for (int m = 1; m <= 8; m <<= 1) {
                #pragma unroll
                for (int j = 0; j < 4; ++j) p[j] += __shfl_xor(p[j], m, 64);
            }
            if (col16 == 0) {
                float b3v = bp3[f];
                #pragma unroll
                for (int j = 0; j < 4; ++j) {
                    int ee = tbase + g * 4 + j;
                    if (ee < n_edges) {
                        float val = p[j] + b3v;
                        float ea = edge_array[4 * ee];
                        if (__builtin_isnan(ea)) val = __builtin_nanf("");
                        out[f * n_edges + ee] = val;
                    }
                }
            }
        }
    }
}

extern "C" void kernel_launch(void* const* d_in, const int* in_sizes, int n_in,
                              void* d_out, int out_size, void* d_ws, size_t ws_size,
                              hipStream_t stream) {
    const float* edge_array = (const float*)d_in[0];
    const float* h_local    = (const float*)d_in[1];
    const float* h_global   = (const float*)d_in[2];
    const float* enc_local  = (const float*)d_in[3];
    const float* enc_global = (const float*)d_in[4];
    const float* W1 = (const float*)d_in[5];
    const float* b1 = (const float*)d_in[6];
    const float* W2 = (const float*)d_in[7];
    const float* b2 = (const float*)d_in[8];
    const float* W3 = (const float*)d_in[9];
    const float* b3 = (const float*)d_in[10];
    const int* addr_from = (const int*)d_in[11];
    const int* addr_to   = (const int*)d_in[12];
    int n_edges = in_sizes[11];
    int n_nodes = in_sizes[1] / 64;
    char* ws = (char*)d_ws;

    hipLaunchKernelGGL(prep_kernel, dim3(114), dim3(256), 0, stream,
                       W1, b1, W2, b2, W3, b3, h_global, enc_global, ws);

    size_t need = (size_t)OFF_HBF + (size_t)n_nodes * 64 * 2;
    bool use_hbf = ws_size >= need;
    if (use_hbf) {
        int n8 = n_nodes * 8;
        hipLaunchKernelGGL(prep_hbf, dim3((n8 + 255) / 256), dim3(256), 0, stream,
                           h_local, (short*)(ws + OFF_HBF), n8);
    }

    int nblk = (n_edges + 511) / 512;
    if (use_hbf) {
        hipLaunchKernelGGL((main_kernel<true>), dim3(nblk), dim3(512), 0, stream,
                           edge_array, h_local, enc_local, addr_from, addr_to,
                           ws, (float*)d_out, n_edges, n_nodes);
    } else {
        hipLaunchKernelGGL((main_kernel<false>), dim3(nblk), dim3(512), 0, stream,
                           edge_array, h_local, enc_local, addr_from, addr_to,
                           ws, (float*)d_out, n_edges, n_nodes);
    }
}

// Round 3
// 41.384 us; speedup vs baseline: 1.5557x; 1.2444x over previous
//
#include <hip/hip_runtime.h>

// LocalDecoder: per-edge gather + 2 stacked MLPs (256->64->64->1), bf16 MFMA.
//
// ws layout (bytes):
//   OFF_W1: bf16 W1frag[2][5][4][64][8]  (f, kk, nn, lane, j)  = 40960
//   OFF_W2: bf16 W2frag[2][2][4][64][8]                        = 16384
//   OFF_B1: f32 bias1p[2][64]  (b1 + h_global/enc_global folded)
//   OFF_B2: f32 b2[2][64];  OFF_W3: f32 w3[2][64];  OFF_B3: f32 b3[2]
//   OFF_HBF: bf16 h_local[n_nodes][64] (prep-converted; only if ws big enough)

#define OFF_W1 0
#define OFF_W2 40960
#define OFF_B1 57344
#define OFF_B2 57856
#define OFF_W3 58368
#define OFF_B3 58880
#define OFF_HBF 59392
#define H1_OFF 58944            // per-wave h1 scratch [16][72] bf16 = 2304 B
#define NWAVE 8
#define LDS_TOTAL (H1_OFF + NWAVE * 2304)
#define PREP_W_BLOCKS 114

typedef __attribute__((ext_vector_type(8))) short bf16x8;
typedef __attribute__((ext_vector_type(4))) float f32x4;

__device__ inline short f2bf(float f) {
    unsigned u = __builtin_bit_cast(unsigned, f);
    u += 0x7FFFu + ((u >> 16) & 1u);      // round-to-nearest-even
    return (short)(u >> 16);
}

__device__ inline float4 ld4(const float* p, bool v) {
    if (v) return *(const float4*)p;
    return make_float4(0.f, 0.f, 0.f, 0.f);
}

__device__ inline bf16x8 pack8(float4 a, float4 b) {
    bf16x8 r;
    r[0] = f2bf(a.x); r[1] = f2bf(a.y); r[2] = f2bf(a.z); r[3] = f2bf(a.w);
    r[4] = f2bf(b.x); r[5] = f2bf(b.y); r[6] = f2bf(b.z); r[7] = f2bf(b.w);
    return r;
}

// ---------------- prep (single kernel): W swizzle + bias fold + h_local->bf16
__global__ void prep_all(const float* __restrict__ W1, const float* __restrict__ b1,
                         const float* __restrict__ W2, const float* __restrict__ b2,
                         const float* __restrict__ W3, const float* __restrict__ b3,
                         const float* __restrict__ h_global, const float* __restrict__ enc_global,
                         const float* __restrict__ h_local, int n8,
                         char* __restrict__ ws) {
    if (blockIdx.x >= PREP_W_BLOCKS) {       // h_local f32 -> bf16 (rows 256B -> 128B)
        int i = (blockIdx.x - PREP_W_BLOCKS) * 256 + threadIdx.x;
        if (i < n8) {
            float4 a = ((const float4*)h_local)[2 * i];
            float4 b = ((const float4*)h_local)[2 * i + 1];
            ((bf16x8*)(ws + OFF_HBF))[i] = pack8(a, b);
        }
        return;
    }
    int idx = blockIdx.x * 256 + threadIdx.x;
    short* w1f = (short*)(ws + OFF_W1);
    short* w2f = (short*)(ws + OFF_W2);
    float* bp1 = (float*)(ws + OFF_B1);
    float* bp2 = (float*)(ws + OFF_B2);
    float* wp3 = (float*)(ws + OFF_W3);
    float* bp3 = (float*)(ws + OFF_B3);
    if (idx < 20480) {                       // W1 fragments, K dims: [gf 0:64 | gt 64:128 | encl 128:160]
        int f = idx / 10240, r0 = idx % 10240;
        int kk = r0 / 2048, r1 = r0 % 2048;
        int nn = r1 / 512,  r2 = r1 % 512;
        int l = r2 / 8,     j = r2 % 8;
        int kt = kk * 32 + (l >> 4) * 8 + j;             // 0..159
        int r = (kt < 128) ? kt : kt + 64;               // enc_local rows live at 192..223
        int c = nn * 16 + (l & 15);
        w1f[idx] = f2bf(W1[(f * 256 + r) * 64 + c]);
    } else if (idx < 28672) {                // W2 fragments
        int i2 = idx - 20480;
        int f = i2 / 4096, r0 = i2 % 4096;
        int kk = r0 / 2048, r1 = r0 % 2048;
        int nn = r1 / 512,  r2 = r1 % 512;
        int l = r2 / 8,     j = r2 % 8;
        int k = kk * 32 + (l >> 4) * 8 + j;
        int c = nn * 16 + (l & 15);
        w2f[i2] = f2bf(W2[(f * 64 + k) * 64 + c]);
    } else if (idx < 28800) {                // bias1' = b1 + globals @ W1 (full fp32)
        int i3 = idx - 28672; int f = i3 / 64, o = i3 % 64;
        float s = b1[f * 64 + o];
        for (int t = 0; t < 64; ++t) s += h_global[t] * W1[(f * 256 + 128 + t) * 64 + o];
        for (int t = 0; t < 32; ++t) s += enc_global[t] * W1[(f * 256 + 224 + t) * 64 + o];
        bp1[i3] = s;
    } else if (idx < 28928) {
        int i4 = idx - 28800; bp2[i4] = b2[i4];
    } else if (idx < 29056) {
        int i5 = idx - 28928; wp3[i5] = W3[i5];          // W3 is [2][64][1]
    } else if (idx < 29058) {
        bp3[idx - 29056] = b3[idx - 29056];
    }
}

// ---------------- guarded tile gather (per-lane fill-0 semantics)
template<bool HBF>
__device__ inline void load_tile(int tbase, int n_edges, int n_nodes,
        const int* __restrict__ addr_from, const int* __restrict__ addr_to,
        const float* __restrict__ h_local, const short* __restrict__ hbf,
        const float* __restrict__ enc_local, int col16, int g,
        bf16x8& f0, bf16x8& f1, bf16x8& t0, bf16x8& t1, float4& e0, float4& e1) {
    int e = tbase + col16;
    bool ev = e < n_edges;
    int af = ev ? addr_from[e] : -1;
    int at = ev ? addr_to[e] : -1;
    bool afv = (unsigned)af < (unsigned)n_nodes;
    bool atv = (unsigned)at < (unsigned)n_nodes;
    if (HBF) {
        bf16x8 z = {0, 0, 0, 0, 0, 0, 0, 0};
        const short* pf = hbf + (size_t)(afv ? af : 0) * 64 + g * 8;
        const short* pt = hbf + (size_t)(atv ? at : 0) * 64 + g * 8;
        bf16x8 v0 = *(const bf16x8*)pf, v1 = *(const bf16x8*)(pf + 32);
        bf16x8 w0 = *(const bf16x8*)pt, w1 = *(const bf16x8*)(pt + 32);
        f0 = afv ? v0 : z; f1 = afv ? v1 : z;
        t0 = atv ? w0 : z; t1 = atv ? w1 : z;
    } else {
        const float* pf = h_local + (size_t)(afv ? af : 0) * 64 + g * 8;
        const float* pt = h_local + (size_t)(atv ? at : 0) * 64 + g * 8;
        f0 = pack8(ld4(pf, afv), ld4(pf + 4, afv));
        f1 = pack8(ld4(pf + 32, afv), ld4(pf + 36, afv));
        t0 = pack8(ld4(pt, atv), ld4(pt + 4, atv));
        t1 = pack8(ld4(pt + 32, atv), ld4(pt + 36, atv));
    }
    const float* pe = enc_local + (size_t)(ev ? e : 0) * 32 + g * 8;
    e0 = ld4(pe, ev); e1 = ld4(pe + 4, ev);
}

// ---------------- main: 8 waves x 1 tile x 16 edges = 128 edges/block
template<bool HBF>
__global__ __launch_bounds__(512, 4) void main_kernel(
        const float* __restrict__ edge_array, const float* __restrict__ h_local,
        const float* __restrict__ enc_local,
        const int* __restrict__ addr_from, const int* __restrict__ addr_to,
        const char* __restrict__ ws, float* __restrict__ out,
        int n_edges, int n_nodes) {
    __shared__ __align__(16) char lds[LDS_TOTAL];
    const int tid = threadIdx.x;
    const int lane = tid & 63, wave = tid >> 6;
    const int col16 = lane & 15, g = lane >> 4;
    const short* hbf = (const short*)(ws + OFF_HBF);
    const int tbase = blockIdx.x * 128 + wave * 16;

    // issue gathers BEFORE the staging barrier (latency overlaps staging)
    bf16x8 nf0, nf1, nt0, nt1; float4 ne0, ne1;
    load_tile<HBF>(tbase, n_edges, n_nodes, addr_from, addr_to, h_local, hbf,
                   enc_local, col16, g, nf0, nf1, nt0, nt1, ne0, ne1);
    int e = tbase + col16;
    float ea = (e < n_edges) ? edge_array[4 * e] : 0.f;   // coalesced NaN probe

    // stage prepped W block into LDS (linear float4 copy)
    #pragma unroll
    for (int it = 0; it < 7; ++it)
        ((float4*)lds)[it * 512 + tid] = ((const float4*)ws)[it * 512 + tid];
    if (tid < 100)
        ((float4*)(lds + 57344))[tid] = ((const float4*)(ws + 57344))[tid];
    __syncthreads();

    if (tbase >= n_edges) return;                        // wave-uniform (after barrier)

    unsigned long long nanmask = __ballot(__builtin_isnan(ea));  // bit i (i<16) = edge tbase+i

    const float* bp1 = (const float*)(lds + OFF_B1);
    const float* bp2 = (const float*)(lds + OFF_B2);
    const float* wp3 = (const float*)(lds + OFF_W3);
    const float* bp3 = (const float*)(lds + OFF_B3);
    short* h1w = (short*)(lds + H1_OFF + wave * 2304);   // [16][72] bf16

    bf16x8 a1[5];
    a1[0] = nf0; a1[1] = nf1; a1[2] = nt0; a1[3] = nt1;
    a1[4] = pack8(ne0, ne1);

    #pragma unroll
    for (int f = 0; f < 2; ++f) {
        f32x4 zero = {0.f, 0.f, 0.f, 0.f};
        f32x4 acc1[4] = {zero, zero, zero, zero};
        #pragma unroll
        for (int kk = 0; kk < 5; ++kk)
            #pragma unroll
            for (int nn = 0; nn < 4; ++nn) {
                bf16x8 b = *(const bf16x8*)(lds + OFF_W1 + ((f * 5 + kk) * 4 + nn) * 1024 + lane * 16);
                acc1[nn] = __builtin_amdgcn_mfma_f32_16x16x32_bf16(a1[kk], b, acc1[nn], 0, 0, 0);
            }

        // bias + leaky_relu, write h1 to LDS (D layout: row=g*4+j (edge), col=col16+16nn)
        #pragma unroll
        for (int nn = 0; nn < 4; ++nn) {
            float bv = bp1[f * 64 + col16 + 16 * nn];
            #pragma unroll
            for (int j = 0; j < 4; ++j) {
                float v = acc1[nn][j] + bv;
                v = fmaxf(v, 0.01f * v);
                h1w[(g * 4 + j) * 72 + col16 + 16 * nn] = f2bf(v);
            }
        }
        asm volatile("s_waitcnt lgkmcnt(0)" ::: "memory");   // wave-internal LDS transpose

        bf16x8 a2[2];                                // layer-2 A frags: row=col16 (edge), k=g*8+j
        a2[0] = *(const bf16x8*)((const char*)h1w + col16 * 144 + g * 16);
        a2[1] = *(const bf16x8*)((const char*)h1w + col16 * 144 + 64 + g * 16);

        f32x4 acc2[4] = {zero, zero, zero, zero};
        #pragma unroll
        for (int kk = 0; kk < 2; ++kk)
            #pragma unroll
            for (int nn = 0; nn < 4; ++nn) {
                bf16x8 b = *(const bf16x8*)(lds + OFF_W2 + ((f * 2 + kk) * 4 + nn) * 1024 + lane * 16);
                acc2[nn] = __builtin_amdgcn_mfma_f32_16x16x32_bf16(a2[kk], b, acc2[nn], 0, 0, 0);
            }

        // layer 3: per-lane partial dot, reduce across the 16 cols
        float p[4] = {0.f, 0.f, 0.f, 0.f};
        #pragma unroll
        for (int nn = 0; nn < 4; ++nn) {
            float b2v = bp2[f * 64 + col16 + 16 * nn];
            float w3v = wp3[f * 64 + col16 + 16 * nn];
            #pragma unroll
            for (int j = 0; j < 4; ++j) {
                float h = acc2[nn][j] + b2v;
                h = fmaxf(h, 0.01f * h);
                p[j] += h * w3v;
            }
        }
        #pragma unroll
        for (int m = 1; m <= 8; m <<= 1) {
            #pragma unroll
            for (int j = 0; j < 4; ++j) p[j] += __shfl_xor(p[j], m, 64);
        }
        if (col16 == 0) {
            float b3v = bp3[f];
            #pragma unroll
            for (int j = 0; j < 4; ++j) {
                int ee = tbase + g * 4 + j;
                if (ee < n_edges) {
                    float val = p[j] + b3v;
                    if ((nanmask >> (g * 4 + j)) & 1ull) val = __builtin_nanf("");
                    out[f * n_edges + ee] = val;
                }
            }
        }
    }
}

extern "C" void kernel_launch(void* const* d_in, const int* in_sizes, int n_in,
                              void* d_out, int out_size, void* d_ws, size_t ws_size,
                              hipStream_t stream) {
    const float* edge_array = (const float*)d_in[0];
    const float* h_local    = (const float*)d_in[1];
    const float* h_global   = (const float*)d_in[2];
    const float* enc_local  = (const float*)d_in[3];
    const float* enc_global = (const float*)d_in[4];
    const float* W1 = (const float*)d_in[5];
    const float* b1 = (const float*)d_in[6];
    const float* W2 = (const float*)d_in[7];
    const float* b2 = (const float*)d_in[8];
    const float* W3 = (const float*)d_in[9];
    const float* b3 = (const float*)d_in[10];
    const int* addr_from = (const int*)d_in[11];
    const int* addr_to   = (const int*)d_in[12];
    int n_edges = in_sizes[11];
    int n_nodes = in_sizes[1] / 64;
    char* ws = (char*)d_ws;

    size_t need = (size_t)OFF_HBF + (size_t)n_nodes * 64 * 2;
    bool use_hbf = ws_size >= need;
    int n8 = n_nodes * 8;
    int prep_blocks = PREP_W_BLOCKS + (use_hbf ? (n8 + 255) / 256 : 0);
    hipLaunchKernelGGL(prep_all, dim3(prep_blocks), dim3(256), 0, stream,
                       W1, b1, W2, b2, W3, b3, h_global, enc_global,
                       h_local, use_hbf ? n8 : 0, ws);

    int nblk = (n_edges + 127) / 128;
    if (use_hbf) {
        hipLaunchKernelGGL((main_kernel<true>), dim3(nblk), dim3(512), 0, stream,
                           edge_array, h_local, enc_local, addr_from, addr_to,
                           ws, (float*)d_out, n_edges, n_nodes);
    } else {
        hipLaunchKernelGGL((main_kernel<false>), dim3(nblk), dim3(512), 0, stream,
                           edge_array, h_local, enc_local, addr_from, addr_to,
                           ws, (float*)d_out, n_edges, n_nodes);
    }
}